// Round 4
// baseline (1744.824 us; speedup 1.0000x reference)
//
#include <hip/hip_runtime.h>
#include <hip/hip_fp16.h>
#include <math.h>

#define BN_EPS 1e-5f
#define HF 32          // hidden features
#define BS 256         // nodes per bucket (8-bit dloc)
#define ASTR 33        // LDS acc row stride (bank spread)
#define KEDGE 4096     // edges per binsort block
#define MAXNB 1024     // max buckets supported by binsort LDS

// ================= tiny utils =================

__global__ void k_zero(int* __restrict__ p, int n) {
    int i = blockIdx.x * blockDim.x + threadIdx.x;
    if (i < n) p[i] = 0;
}

// ================= Phase A: block-local counting sort into buckets =================
// Each block sorts KEDGE edges by bucket (dst>>8) in LDS, reserves one global
// cursor range per bucket-run, writes runs out as contiguous 8B-record bursts.

__global__ __launch_bounds__(256) void k_binsort(
        const int* __restrict__ src, const int* __restrict__ dst,
        const float* __restrict__ ew, int E, int NB, int bcap,
        int* __restrict__ gcur, uint2* __restrict__ recs) {
    __shared__ uint2 srec[KEDGE];
    __shared__ unsigned short sbk[KEDGE];
    __shared__ int hist[MAXNB], excl[MAXNB], curs[MAXNB], sbase[MAXNB];

    int tid = threadIdx.x;
    int base = blockIdx.x * KEDGE;
    int cnt = min(KEDGE, E - base);

    for (int i = tid; i < NB; i += 256) hist[i] = 0;
    __syncthreads();

    // pass 1: histogram
    for (int i = tid; i < cnt; i += 256)
        atomicAdd(&hist[dst[base + i] >> 8], 1);
    __syncthreads();

    // exclusive scan over NB buckets (wave 0 only)
    if (tid < 64) {
        int run = 0;
        for (int c = 0; c < NB; c += 64) {
            int idx = c + tid;
            int v = (idx < NB) ? hist[idx] : 0;
            int incl = v;
#pragma unroll
            for (int o = 1; o < 64; o <<= 1) {
                int up = __shfl_up(incl, o, 64);
                if (tid >= o) incl += up;
            }
            if (idx < NB) { int e = run + incl - v; excl[idx] = e; curs[idx] = e; }
            run += __shfl(incl, 63, 64);
        }
    }
    __syncthreads();

    // pass 2: scatter into sorted LDS order
    for (int i = tid; i < cnt; i += 256) {
        int s = src[base + i];
        int d = dst[base + i];
        float w = ew[base + i];
        int b = d >> 8;
        int pos = atomicAdd(&curs[b], 1);
        srec[pos] = make_uint2(((unsigned)s << 8) | (unsigned)(d & 255), __float_as_uint(w));
        sbk[pos] = (unsigned short)b;
    }
    __syncthreads();

    // reserve global space, one atomic per non-empty bucket-run
    for (int b = tid; b < NB; b += 256) {
        int len = hist[b];
        sbase[b] = len ? atomicAdd(&gcur[b], len) : 0;
    }
    __syncthreads();

    // copy out: contiguous within each run -> dense line writes
    for (int i = tid; i < cnt; i += 256) {
        int b = sbk[i];
        int off = sbase[b] + (i - excl[b]);
        if (off < bcap) recs[(size_t)b * bcap + off] = srec[i];
    }
}

// ================= Phase B0: degree -> dinv per bucket =================

__global__ __launch_bounds__(256) void k_deg(
        const uint2* __restrict__ recs, const int* __restrict__ gcur, int bcap,
        float* __restrict__ dinv, int n) {
    __shared__ float sdeg[BS];
    int b = blockIdx.x, tid = threadIdx.x;
    if (tid < BS) sdeg[tid] = 1.0f;  // self-loop weight
    __syncthreads();
    int cnt = min(gcur[b], bcap);
    const uint2* r = recs + (size_t)b * bcap;
    for (int i = tid; i < cnt; i += 256) {
        uint2 rec = r[i];
        atomicAdd(&sdeg[rec.x & 255], __uint_as_float(rec.y));
    }
    __syncthreads();
    if (tid < BS) {
        int g = b * BS + tid;
        if (g < n) dinv[g] = rsqrtf(sdeg[tid]);
    }
}

// ================= dense feature transforms (fp16 out) =================

__global__ void k_xw1_h(const float* __restrict__ x, const float* __restrict__ W,
                        __half* __restrict__ out, int n) {
    int idx = blockIdx.x * blockDim.x + threadIdx.x;
    if (idx >= n * HF) return;
    int nn = idx >> 5, f = idx & 31;
    const float4 xr = *(const float4*)(x + (size_t)nn * 4);
    float acc = xr.x * W[f] + xr.y * W[32 + f] + xr.z * W[64 + f] + xr.w * W[96 + f];
    out[idx] = __float2half(acc);
}

__global__ void k_xw2_h(const float* __restrict__ Hin, const float* __restrict__ W,
                        __half* __restrict__ out, int n) {
    __shared__ float sW[32 * 32];
    __shared__ float sH[8][32];
    int tid = threadIdx.x;
    for (int i = tid; i < 1024; i += 256) sW[i] = W[i];
    int r = tid >> 5, f = tid & 31;
    int nn = blockIdx.x * 8 + r;
    if (nn < n) sH[r][f] = Hin[(size_t)nn * HF + f];
    __syncthreads();
    if (nn >= n) return;
    float acc = 0.0f;
#pragma unroll
    for (int k = 0; k < 32; ++k) acc += sH[r][k] * sW[k * 32 + f];
    out[(size_t)nn * HF + f] = __float2half(acc);
}

// ================= Phase B: bucket aggregation with LDS accumulators =================
// One block per bucket. Each thread processes whole records: 64B fp16 row load,
// 32 ds_add_f32 into acc[dloc]. Fused self-loop + bias/ReLU/BN epilogue.

__global__ __launch_bounds__(512) void k_agg(
        const uint2* __restrict__ recs, const int* __restrict__ gcur, int bcap,
        const float* __restrict__ dinv, const __half* __restrict__ A,
        const float* __restrict__ bias, const float* __restrict__ gamma,
        const float* __restrict__ beta, const float* __restrict__ mean,
        const float* __restrict__ var,
        float* __restrict__ Hout, int n) {
    __shared__ float acc[BS * ASTR];
    __shared__ float sdinv[BS];
    int b = blockIdx.x, tid = threadIdx.x;

    for (int i = tid; i < BS * ASTR; i += 512) acc[i] = 0.0f;
    if (tid < BS) {
        int g = b * BS + tid;
        sdinv[tid] = (g < n) ? dinv[g] : 0.0f;
    }
    __syncthreads();

    int cnt = min(gcur[b], bcap);
    const uint2* r = recs + (size_t)b * bcap;
    for (int i = tid; i < cnt; i += 512) {
        uint2 rec = r[i];
        int dloc = rec.x & 255;
        int s = rec.x >> 8;
        float w = __uint_as_float(rec.y);
        float nrm = w * dinv[s] * sdinv[dloc];
        union { uint4 q[4]; unsigned u[16]; } row;
        const uint4* Ar = (const uint4*)(A + ((size_t)s << 5));
        row.q[0] = Ar[0]; row.q[1] = Ar[1]; row.q[2] = Ar[2]; row.q[3] = Ar[3];
        float* ap = acc + dloc * ASTR;
#pragma unroll
        for (int k2 = 0; k2 < 16; ++k2) {
            float2 f = __half22float2(*(const __half2*)&row.u[k2]);
            atomicAdd(&ap[2 * k2], nrm * f.x);
            atomicAdd(&ap[2 * k2 + 1], nrm * f.y);
        }
    }
    __syncthreads();

    // epilogue: self-loop + bias + relu + BN, coalesced float4 stores
    for (int u = tid; u < BS * 8; u += 512) {
        int dloc = u >> 3, fq = (u & 7) * 4;
        int g = b * BS + dloc;
        if (g >= n) continue;
        float dig = sdinv[dloc];
        float sl = dig * dig;
        const __half2* hr = (const __half2*)(A + ((size_t)g << 5) + fq);
        float2 s0 = __half22float2(hr[0]), s1 = __half22float2(hr[1]);
        const float* ap = acc + dloc * ASTR + fq;
        float a0 = ap[0] + sl * s0.x;
        float a1 = ap[1] + sl * s0.y;
        float a2 = ap[2] + sl * s1.x;
        float a3 = ap[3] + sl * s1.y;
        float4 o;
        o.x = (fmaxf(a0 + bias[fq + 0], 0.0f) - mean[fq + 0]) * gamma[fq + 0] * rsqrtf(var[fq + 0] + BN_EPS) + beta[fq + 0];
        o.y = (fmaxf(a1 + bias[fq + 1], 0.0f) - mean[fq + 1]) * gamma[fq + 1] * rsqrtf(var[fq + 1] + BN_EPS) + beta[fq + 1];
        o.z = (fmaxf(a2 + bias[fq + 2], 0.0f) - mean[fq + 2]) * gamma[fq + 2] * rsqrtf(var[fq + 2] + BN_EPS) + beta[fq + 2];
        o.w = (fmaxf(a3 + bias[fq + 3], 0.0f) - mean[fq + 3]) * gamma[fq + 3] * rsqrtf(var[fq + 3] + BN_EPS) + beta[fq + 3];
        *(float4*)(Hout + ((size_t)g << 5) + fq) = o;
    }
}

// ================= fused head: LSTM1 + LSTM2 + linear =================

__global__ __launch_bounds__(256) void k_head(
        const float* __restrict__ h1, const float* __restrict__ h2,
        const float* __restrict__ x,
        const float* __restrict__ wih1, const float* __restrict__ bih1, const float* __restrict__ bhh1,
        const float* __restrict__ wih2, const float* __restrict__ bih2, const float* __restrict__ bhh2,
        const float* __restrict__ lw, const float* __restrict__ lb,
        float* __restrict__ out, int n) {
    __shared__ float sH1[32 * 256];
    int tid = threadIdx.x;
    int nn = blockIdx.x * 256 + tid;
    bool act = nn < n;

    float skip[64];
    if (act) {
        const float4* a = (const float4*)(h1 + (size_t)nn * HF);
        const float4* b = (const float4*)(h2 + (size_t)nn * HF);
#pragma unroll
        for (int q = 0; q < 8; ++q) {
            float4 v = a[q];
            skip[4 * q] = v.x; skip[4 * q + 1] = v.y; skip[4 * q + 2] = v.z; skip[4 * q + 3] = v.w;
        }
#pragma unroll
        for (int q = 0; q < 8; ++q) {
            float4 v = b[q];
            skip[32 + 4 * q] = v.x; skip[33 + 4 * q] = v.y; skip[34 + 4 * q] = v.z; skip[35 + 4 * q] = v.w;
        }
    } else {
#pragma unroll
        for (int q = 0; q < 64; ++q) skip[q] = 0.0f;
    }

#pragma unroll 2
    for (int j = 0; j < 32; ++j) {
        const float4* wi = (const float4*)(wih1 + (size_t)j * 64);
        const float4* wg = (const float4*)(wih1 + (size_t)(64 + j) * 64);
        const float4* wo = (const float4*)(wih1 + (size_t)(96 + j) * 64);
        float gi = bih1[j] + bhh1[j];
        float gg = bih1[64 + j] + bhh1[64 + j];
        float go = bih1[96 + j] + bhh1[96 + j];
#pragma unroll
        for (int q = 0; q < 16; ++q) {
            float4 a = wi[q], b = wg[q], c = wo[q];
            float s0 = skip[4 * q], s1 = skip[4 * q + 1], s2 = skip[4 * q + 2], s3 = skip[4 * q + 3];
            gi += a.x * s0 + a.y * s1 + a.z * s2 + a.w * s3;
            gg += b.x * s0 + b.y * s1 + b.z * s2 + b.w * s3;
            go += c.x * s0 + c.y * s1 + c.z * s2 + c.w * s3;
        }
        float cc = tanhf(gg) / (1.0f + __expf(-gi));
        float hh = tanhf(cc) / (1.0f + __expf(-go));
        sH1[j * 256 + tid] = hh;
    }

    float H1v[32];
#pragma unroll
    for (int k = 0; k < 32; ++k) H1v[k] = sH1[k * 256 + tid];

    float oa = lb[0];
#pragma unroll
    for (int k = 0; k < 32; ++k) oa += fmaxf(H1v[k], 0.0f) * lw[k];

#pragma unroll 2
    for (int j = 0; j < 32; ++j) {
        const float4* wi = (const float4*)(wih2 + (size_t)j * 32);
        const float4* wg = (const float4*)(wih2 + (size_t)(64 + j) * 32);
        const float4* wo = (const float4*)(wih2 + (size_t)(96 + j) * 32);
        float gi = bih2[j] + bhh2[j];
        float gg = bih2[64 + j] + bhh2[64 + j];
        float go = bih2[96 + j] + bhh2[96 + j];
#pragma unroll
        for (int q = 0; q < 8; ++q) {
            float4 a = wi[q], b = wg[q], c = wo[q];
            float s0 = H1v[4 * q], s1 = H1v[4 * q + 1], s2 = H1v[4 * q + 2], s3 = H1v[4 * q + 3];
            gi += a.x * s0 + a.y * s1 + a.z * s2 + a.w * s3;
            gg += b.x * s0 + b.y * s1 + b.z * s2 + b.w * s3;
            go += c.x * s0 + c.y * s1 + c.z * s2 + c.w * s3;
        }
        float cc = tanhf(gg) / (1.0f + __expf(-gi));
        float hh = tanhf(cc) / (1.0f + __expf(-go));
        oa += fmaxf(hh, 0.0f) * lw[32 + j];
    }

    if (act) {
        const float4 xv = *(const float4*)(x + (size_t)nn * 4);
        oa += fmaxf(xv.x, 0.0f) * lw[64] + fmaxf(xv.y, 0.0f) * lw[65] +
              fmaxf(xv.z, 0.0f) * lw[66] + fmaxf(xv.w, 0.0f) * lw[67];
        out[nn] = oa;
    }
}

// ================= fallback (atomic scatter, fp32) =================

__global__ void k_initdeg(float* __restrict__ deg, int n) {
    int i = blockIdx.x * blockDim.x + threadIdx.x;
    if (i < n) deg[i] = 1.0f;
}

__global__ void k_deg_only(const int* __restrict__ dst, const float* __restrict__ ew,
                           float* __restrict__ deg, int E) {
    int e = blockIdx.x * blockDim.x + threadIdx.x;
    if (e < E) atomicAdd(&deg[dst[e]], ew[e]);
}

__global__ void k_dinv_f(float* __restrict__ deg, int n) {
    int i = blockIdx.x * blockDim.x + threadIdx.x;
    if (i < n) {
        float d = deg[i];
        deg[i] = d > 0.0f ? rsqrtf(d) : 0.0f;
    }
}

__global__ void k_xw1_f(const float* __restrict__ x, const float* __restrict__ W,
                        float* __restrict__ out, int n) {
    int idx = blockIdx.x * blockDim.x + threadIdx.x;
    if (idx >= n * HF) return;
    int nn = idx >> 5, f = idx & 31;
    const float4 xr = *(const float4*)(x + (size_t)nn * 4);
    out[idx] = xr.x * W[f] + xr.y * W[32 + f] + xr.z * W[64 + f] + xr.w * W[96 + f];
}

__global__ void k_xw2_f(const float* __restrict__ Hin, const float* __restrict__ W,
                        float* __restrict__ out, int n) {
    __shared__ float sW[32 * 32];
    __shared__ float sH[8][32];
    int tid = threadIdx.x;
    for (int i = tid; i < 1024; i += 256) sW[i] = W[i];
    int r = tid >> 5, f = tid & 31;
    int nn = blockIdx.x * 8 + r;
    if (nn < n) sH[r][f] = Hin[(size_t)nn * HF + f];
    __syncthreads();
    if (nn >= n) return;
    float acc = 0.0f;
#pragma unroll
    for (int k = 0; k < 32; ++k) acc += sH[r][k] * sW[k * 32 + f];
    out[(size_t)nn * HF + f] = acc;
}

__global__ void k_selfloop(const float* __restrict__ A, const float* __restrict__ dinv,
                           float* __restrict__ B, int n) {
    int idx = blockIdx.x * blockDim.x + threadIdx.x;
    if (idx >= n * HF) return;
    int nn = idx >> 5;
    float di = dinv[nn];
    B[idx] = di * di * A[idx];
}

__global__ void k_scatter(const int* __restrict__ src, const int* __restrict__ dst,
                          const float* __restrict__ ew, const float* __restrict__ dinv,
                          const float* __restrict__ A, float* __restrict__ B, int total) {
    int idx = blockIdx.x * blockDim.x + threadIdx.x;
    if (idx >= total) return;
    int e = idx >> 5, f = idx & 31;
    int s = src[e], d = dst[e];
    float norm = dinv[s] * ew[e] * dinv[d];
    atomicAdd(&B[d * HF + f], norm * A[s * HF + f]);
}

__global__ void k_post(const float* __restrict__ B, const float* __restrict__ bias,
                       const float* __restrict__ gamma, const float* __restrict__ beta,
                       const float* __restrict__ mean, const float* __restrict__ var,
                       float* __restrict__ Hout, int n) {
    int idx = blockIdx.x * blockDim.x + threadIdx.x;
    if (idx >= n * HF) return;
    int f = idx & 31;
    float v = fmaxf(B[idx] + bias[f], 0.0f);
    float sc = gamma[f] * rsqrtf(var[f] + BN_EPS);
    Hout[idx] = (v - mean[f]) * sc + beta[f];
}

// ================= launch =================

extern "C" void kernel_launch(void* const* d_in, const int* in_sizes, int n_in,
                              void* d_out, int out_size, void* d_ws, size_t ws_size,
                              hipStream_t stream) {
    const float* x   = (const float*)d_in[0];
    const int*   ei  = (const int*)d_in[1];
    const float* ew  = (const float*)d_in[2];
    const float* g1w = (const float*)d_in[3];
    const float* g1b = (const float*)d_in[4];
    const float* g2w = (const float*)d_in[5];
    const float* g2b = (const float*)d_in[6];
    const float* bn1g = (const float*)d_in[7];
    const float* bn1b = (const float*)d_in[8];
    const float* bn1m = (const float*)d_in[9];
    const float* bn1v = (const float*)d_in[10];
    const float* bn2g = (const float*)d_in[11];
    const float* bn2b = (const float*)d_in[12];
    const float* bn2m = (const float*)d_in[13];
    const float* bn2v = (const float*)d_in[14];
    const float* w1ih = (const float*)d_in[15];
    const float* b1ih = (const float*)d_in[17];
    const float* b1hh = (const float*)d_in[18];
    const float* w2ih = (const float*)d_in[19];
    const float* b2ih = (const float*)d_in[21];
    const float* b2hh = (const float*)d_in[22];
    const float* lw   = (const float*)d_in[23];
    const float* lb   = (const float*)d_in[24];
    float* out = (float*)d_out;

    const int N = in_sizes[0] / 4;
    const int E = in_sizes[2];
    const int* src = ei;
    const int* dst = ei + E;

    const int T = 256;
    const int NB = (N + BS - 1) / BS;
    long long meanb = ((long long)BS * E) / (N > 0 ? N : 1);
    int bcap = (int)(meanb + meanb / 4 + 128);

    // workspace layout (256B-aligned regions)
    char* p = (char*)d_ws;
    auto alloc = [&](size_t bytes) { char* q = p; p += (bytes + 255) & ~(size_t)255; return q; };
    int*      gcur = (int*)alloc(sizeof(int) * NB);
    uint2*    recs = (uint2*)alloc(sizeof(uint2) * (size_t)NB * bcap);
    float*    dinv = (float*)alloc(sizeof(float) * N);
    __half*   A    = (__half*)alloc(sizeof(__half) * (size_t)N * HF);
    float*    C    = (float*)alloc(sizeof(float) * (size_t)N * HF);   // h1
    float*    B2   = (float*)alloc(sizeof(float) * (size_t)N * HF);   // h2
    size_t need = (size_t)(p - (char*)d_ws);

    int bN  = (N + T - 1) / T;
    int bE  = (E + T - 1) / T;
    int bNF = (N * HF + T - 1) / T;
    int bN8 = (N + 7) / 8;
    int bH  = (N + 255) / 256;
    int bBin = (E + KEDGE - 1) / KEDGE;

    if (ws_size >= need && NB <= MAXNB && N <= (1 << 24)) {
        // ---- build: sort edges into buckets, then degrees ----
        k_zero<<<(NB + T - 1) / T, T, 0, stream>>>(gcur, NB);
        k_binsort<<<bBin, T, 0, stream>>>(src, dst, ew, E, NB, bcap, gcur, recs);
        k_deg<<<NB, T, 0, stream>>>(recs, gcur, bcap, dinv, N);

        // ---- layer 1 ----
        k_xw1_h<<<bNF, T, 0, stream>>>(x, g1w, A, N);
        k_agg<<<NB, 512, 0, stream>>>(recs, gcur, bcap, dinv, A,
                                      g1b, bn1g, bn1b, bn1m, bn1v, C, N);
        // ---- layer 2 ----
        k_xw2_h<<<bN8, T, 0, stream>>>(C, g2w, A, N);
        k_agg<<<NB, 512, 0, stream>>>(recs, gcur, bcap, dinv, A,
                                      g2b, bn2g, bn2b, bn2m, bn2v, B2, N);
        // ---- head ----
        k_head<<<bH, T, 0, stream>>>(C, B2, x, w1ih, b1ih, b1hh, w2ih, b2ih, b2hh,
                                     lw, lb, out, N);
    } else {
        // ---- fallback: atomic scatter, fp32 ----
        size_t Npad = ((size_t)N + 255) & ~(size_t)255;
        float* fdinv = (float*)d_ws;
        float* fA = fdinv + Npad;
        float* fB = fA + (size_t)N * HF;
        float* fC = fB + (size_t)N * HF;
        int bEF = (int)(((long long)E * HF + T - 1) / T);

        k_initdeg<<<bN, T, 0, stream>>>(fdinv, N);
        k_deg_only<<<bE, T, 0, stream>>>(dst, ew, fdinv, E);
        k_dinv_f<<<bN, T, 0, stream>>>(fdinv, N);

        k_xw1_f<<<bNF, T, 0, stream>>>(x, g1w, fA, N);
        k_selfloop<<<bNF, T, 0, stream>>>(fA, fdinv, fB, N);
        k_scatter<<<bEF, T, 0, stream>>>(src, dst, ew, fdinv, fA, fB, E * HF);
        k_post<<<bNF, T, 0, stream>>>(fB, g1b, bn1g, bn1b, bn1m, bn1v, fC, N);

        k_xw2_f<<<bN8, T, 0, stream>>>(fC, g2w, fA, N);
        k_selfloop<<<bNF, T, 0, stream>>>(fA, fdinv, fB, N);
        k_scatter<<<bEF, T, 0, stream>>>(src, dst, ew, fdinv, fA, fB, E * HF);
        k_post<<<bNF, T, 0, stream>>>(fB, g2b, bn2g, bn2b, bn2m, bn2v, fB, N);

        k_head<<<bH, T, 0, stream>>>(fC, fB, x, w1ih, b1ih, b1hh, w2ih, b2ih, b2hh,
                                     lw, lb, out, N);
    }
}

// Round 5
// 568.061 us; speedup vs baseline: 3.0715x; 3.0715x over previous
//
#include <hip/hip_runtime.h>
#include <hip/hip_fp16.h>
#include <math.h>

#define BN_EPS 1e-5f
#define HF 32          // hidden features
#define BS 256         // nodes per bucket (8-bit dloc)
#define KEDGE 4096     // edges per binsort block
#define MAXNB 1024     // max buckets supported by binsort LDS
#define BCAPS 5632     // max records per bucket held in k_sortb LDS

// ================= tiny utils =================

__global__ void k_zero(int* __restrict__ p, int n) {
    int i = blockIdx.x * blockDim.x + threadIdx.x;
    if (i < n) p[i] = 0;
}

// ================= Phase A: block-local counting sort into buckets =================
// Each block sorts KEDGE edges by bucket (dst>>8) in LDS, reserves one global
// cursor range per bucket-run, writes runs out as contiguous 8B-record bursts.

__global__ __launch_bounds__(256) void k_binsort(
        const int* __restrict__ src, const int* __restrict__ dst,
        const float* __restrict__ ew, int E, int NB, int bcap,
        int* __restrict__ gcur, uint2* __restrict__ recs) {
    __shared__ uint2 srec[KEDGE];
    __shared__ unsigned short sbk[KEDGE];
    __shared__ int hist[MAXNB], excl[MAXNB], curs[MAXNB], sbase[MAXNB];

    int tid = threadIdx.x;
    int base = blockIdx.x * KEDGE;
    int cnt = min(KEDGE, E - base);

    for (int i = tid; i < NB; i += 256) hist[i] = 0;
    __syncthreads();

    for (int i = tid; i < cnt; i += 256)
        atomicAdd(&hist[dst[base + i] >> 8], 1);
    __syncthreads();

    if (tid < 64) {
        int run = 0;
        for (int c = 0; c < NB; c += 64) {
            int idx = c + tid;
            int v = (idx < NB) ? hist[idx] : 0;
            int incl = v;
#pragma unroll
            for (int o = 1; o < 64; o <<= 1) {
                int up = __shfl_up(incl, o, 64);
                if (tid >= o) incl += up;
            }
            if (idx < NB) { int e = run + incl - v; excl[idx] = e; curs[idx] = e; }
            run += __shfl(incl, 63, 64);
        }
    }
    __syncthreads();

    for (int i = tid; i < cnt; i += 256) {
        int s = src[base + i];
        int d = dst[base + i];
        float w = ew[base + i];
        int b = d >> 8;
        int pos = atomicAdd(&curs[b], 1);
        srec[pos] = make_uint2(((unsigned)s << 8) | (unsigned)(d & 255), __float_as_uint(w));
        sbk[pos] = (unsigned short)b;
    }
    __syncthreads();

    for (int b = tid; b < NB; b += 256) {
        int len = hist[b];
        sbase[b] = len ? atomicAdd(&gcur[b], len) : 0;
    }
    __syncthreads();

    for (int i = tid; i < cnt; i += 256) {
        int b = sbk[i];
        int off = sbase[b] + (i - excl[b]);
        if (off < bcap) recs[(size_t)b * bcap + off] = srec[i];
    }
}

// ================= Phase B: in-bucket sort by dst + CSR ptrs + dinv =================
// One block per bucket. Run fits in LDS; sorted write-back stays inside a
// ~42KB L2 window (dense line dirtying). No device atomics.

__global__ __launch_bounds__(512) void k_sortb(
        uint2* __restrict__ recs, const int* __restrict__ gcur, int bcap,
        int* __restrict__ pstart, int* __restrict__ pcnt,
        float* __restrict__ dinv, int n) {
    __shared__ uint2 srec[BCAPS];
    __shared__ int hist[BS], excl[BS], curs[BS];
    __shared__ float wsum[BS];

    int b = blockIdx.x, tid = threadIdx.x;
    int cnt = min(gcur[b], bcap);
    uint2* r = recs + (size_t)b * bcap;

    if (tid < BS) { hist[tid] = 0; wsum[tid] = 1.0f; }  // self-loop weight in wsum
    __syncthreads();

    for (int i = tid; i < cnt; i += 512) {
        uint2 u = r[i];
        srec[i] = u;
        int dl = u.x & 255;
        atomicAdd(&hist[dl], 1);
        atomicAdd(&wsum[dl], __uint_as_float(u.y));
    }
    __syncthreads();

    if (tid < 64) {
        int run = 0;
        for (int c = 0; c < BS; c += 64) {
            int idx = c + tid;
            int v = hist[idx];
            int incl = v;
#pragma unroll
            for (int o = 1; o < 64; o <<= 1) {
                int up = __shfl_up(incl, o, 64);
                if (tid >= o) incl += up;
            }
            int e = run + incl - v;
            excl[idx] = e; curs[idx] = e;
            run += __shfl(incl, 63, 64);
        }
    }
    __syncthreads();

    for (int i = tid; i < cnt; i += 512) {
        uint2 u = srec[i];
        int pos = atomicAdd(&curs[u.x & 255], 1);
        r[pos] = u;
    }

    if (tid < BS) {
        int g = b * BS + tid;
        if (g < n) {
            pstart[g] = b * bcap + excl[tid];
            pcnt[g] = hist[tid];
            dinv[g] = rsqrtf(wsum[tid]);
        }
    }
}

// ================= Phase C: precompute norm per record =================
// rec.y <- w * dinv[src] * dinv[dst]. 4 blocks per bucket.

__global__ __launch_bounds__(256) void k_norm(
        uint2* __restrict__ recs, const int* __restrict__ gcur, int bcap,
        const float* __restrict__ dinv) {
    int b = blockIdx.x >> 2, q = blockIdx.x & 3;
    int cnt = min(gcur[b], bcap);
    int lo = (cnt * q) >> 2, hi = (cnt * (q + 1)) >> 2;
    uint2* r = recs + (size_t)b * bcap;
    float dbase = 0.0f;  // per-record dst dinv read below (L2-hot)
    (void)dbase;
    for (int i = lo + threadIdx.x; i < hi; i += 256) {
        uint2 u = r[i];
        int s = u.x >> 8;
        int g = b * BS + (int)(u.x & 255);
        float w = __uint_as_float(u.y);
        u.y = __float_as_uint(w * dinv[s] * dinv[g]);
        r[i] = u;
    }
}

// ================= dense feature transforms (fp16 out) =================

__global__ void k_xw1_h(const float* __restrict__ x, const float* __restrict__ W,
                        __half* __restrict__ out, int n) {
    int idx = blockIdx.x * blockDim.x + threadIdx.x;
    if (idx >= n * HF) return;
    int nn = idx >> 5, f = idx & 31;
    const float4 xr = *(const float4*)(x + (size_t)nn * 4);
    float acc = xr.x * W[f] + xr.y * W[32 + f] + xr.z * W[64 + f] + xr.w * W[96 + f];
    out[idx] = __float2half(acc);
}

__global__ void k_xw2_h(const float* __restrict__ Hin, const float* __restrict__ W,
                        __half* __restrict__ out, int n) {
    __shared__ float sW[32 * 32];
    __shared__ float sH[8][32];
    int tid = threadIdx.x;
    for (int i = tid; i < 1024; i += 256) sW[i] = W[i];
    int r = tid >> 5, f = tid & 31;
    int nn = blockIdx.x * 8 + r;
    if (nn < n) sH[r][f] = Hin[(size_t)nn * HF + f];
    __syncthreads();
    if (nn >= n) return;
    float acc = 0.0f;
#pragma unroll
    for (int k = 0; k < 32; ++k) acc += sH[r][k] * sW[k * 32 + f];
    out[(size_t)nn * HF + f] = __float2half(acc);
}

// ================= gather: per-node CSR aggregation + fused epilogue =================
// 4 lanes per node, 8 features per lane (16B fp16 loads). Records contiguous,
// norms precomputed. No LDS, no atomics.

__global__ __launch_bounds__(256) void k_gather(
        const uint2* __restrict__ recs, const int* __restrict__ pstart,
        const int* __restrict__ pcnt, const float* __restrict__ dinv,
        const __half* __restrict__ A,
        const float* __restrict__ bias, const float* __restrict__ gamma,
        const float* __restrict__ beta, const float* __restrict__ mean,
        const float* __restrict__ var,
        float* __restrict__ Hout, int n) {
    int g = blockIdx.x * 64 + (threadIdx.x >> 2);
    int lane = threadIdx.x & 3;
    if (g >= n) return;

    float dig = dinv[g];
    float sl = dig * dig;
    uint4 srow = ((const uint4*)(A + ((size_t)g << 5)))[lane];
    float acc[8];
    {
        const __half2* h = (const __half2*)&srow;
#pragma unroll
        for (int k = 0; k < 4; ++k) {
            float2 f = __half22float2(h[k]);
            acc[2 * k] = sl * f.x; acc[2 * k + 1] = sl * f.y;
        }
    }

    int cn = pcnt[g];
    const uint2* r = recs + pstart[g];
    int e = 0;
    for (; e + 2 <= cn; e += 2) {
        uint2 r0 = r[e], r1 = r[e + 1];
        uint4 row0 = ((const uint4*)(A + ((size_t)(r0.x >> 8) << 5)))[lane];
        uint4 row1 = ((const uint4*)(A + ((size_t)(r1.x >> 8) << 5)))[lane];
        float n0 = __uint_as_float(r0.y), n1 = __uint_as_float(r1.y);
        const __half2* h0 = (const __half2*)&row0;
        const __half2* h1 = (const __half2*)&row1;
#pragma unroll
        for (int k = 0; k < 4; ++k) {
            float2 f0 = __half22float2(h0[k]);
            float2 f1 = __half22float2(h1[k]);
            acc[2 * k]     += n0 * f0.x + n1 * f1.x;
            acc[2 * k + 1] += n0 * f0.y + n1 * f1.y;
        }
    }
    if (e < cn) {
        uint2 r0 = r[e];
        uint4 row0 = ((const uint4*)(A + ((size_t)(r0.x >> 8) << 5)))[lane];
        float n0 = __uint_as_float(r0.y);
        const __half2* h0 = (const __half2*)&row0;
#pragma unroll
        for (int k = 0; k < 4; ++k) {
            float2 f0 = __half22float2(h0[k]);
            acc[2 * k]     += n0 * f0.x;
            acc[2 * k + 1] += n0 * f0.y;
        }
    }

    int fq = lane * 8;
    float o[8];
#pragma unroll
    for (int k = 0; k < 8; ++k) {
        float v = fmaxf(acc[k] + bias[fq + k], 0.0f);
        o[k] = (v - mean[fq + k]) * gamma[fq + k] * rsqrtf(var[fq + k] + BN_EPS) + beta[fq + k];
    }
    float* dst = Hout + ((size_t)g << 5) + fq;
    *(float4*)dst = make_float4(o[0], o[1], o[2], o[3]);
    *(float4*)(dst + 4) = make_float4(o[4], o[5], o[6], o[7]);
}

// ================= fused head: LSTM1 + LSTM2 + linear =================

__global__ __launch_bounds__(256) void k_head(
        const float* __restrict__ h1, const float* __restrict__ h2,
        const float* __restrict__ x,
        const float* __restrict__ wih1, const float* __restrict__ bih1, const float* __restrict__ bhh1,
        const float* __restrict__ wih2, const float* __restrict__ bih2, const float* __restrict__ bhh2,
        const float* __restrict__ lw, const float* __restrict__ lb,
        float* __restrict__ out, int n) {
    __shared__ float sH1[32 * 256];
    int tid = threadIdx.x;
    int nn = blockIdx.x * 256 + tid;
    bool act = nn < n;

    float skip[64];
    if (act) {
        const float4* a = (const float4*)(h1 + (size_t)nn * HF);
        const float4* b = (const float4*)(h2 + (size_t)nn * HF);
#pragma unroll
        for (int q = 0; q < 8; ++q) {
            float4 v = a[q];
            skip[4 * q] = v.x; skip[4 * q + 1] = v.y; skip[4 * q + 2] = v.z; skip[4 * q + 3] = v.w;
        }
#pragma unroll
        for (int q = 0; q < 8; ++q) {
            float4 v = b[q];
            skip[32 + 4 * q] = v.x; skip[33 + 4 * q] = v.y; skip[34 + 4 * q] = v.z; skip[35 + 4 * q] = v.w;
        }
    } else {
#pragma unroll
        for (int q = 0; q < 64; ++q) skip[q] = 0.0f;
    }

#pragma unroll 2
    for (int j = 0; j < 32; ++j) {
        const float4* wi = (const float4*)(wih1 + (size_t)j * 64);
        const float4* wg = (const float4*)(wih1 + (size_t)(64 + j) * 64);
        const float4* wo = (const float4*)(wih1 + (size_t)(96 + j) * 64);
        float gi = bih1[j] + bhh1[j];
        float gg = bih1[64 + j] + bhh1[64 + j];
        float go = bih1[96 + j] + bhh1[96 + j];
#pragma unroll
        for (int q = 0; q < 16; ++q) {
            float4 a = wi[q], b = wg[q], c = wo[q];
            float s0 = skip[4 * q], s1 = skip[4 * q + 1], s2 = skip[4 * q + 2], s3 = skip[4 * q + 3];
            gi += a.x * s0 + a.y * s1 + a.z * s2 + a.w * s3;
            gg += b.x * s0 + b.y * s1 + b.z * s2 + b.w * s3;
            go += c.x * s0 + c.y * s1 + c.z * s2 + c.w * s3;
        }
        float cc = tanhf(gg) / (1.0f + __expf(-gi));
        float hh = tanhf(cc) / (1.0f + __expf(-go));
        sH1[j * 256 + tid] = hh;
    }

    float H1v[32];
#pragma unroll
    for (int k = 0; k < 32; ++k) H1v[k] = sH1[k * 256 + tid];

    float oa = lb[0];
#pragma unroll
    for (int k = 0; k < 32; ++k) oa += fmaxf(H1v[k], 0.0f) * lw[k];

#pragma unroll 2
    for (int j = 0; j < 32; ++j) {
        const float4* wi = (const float4*)(wih2 + (size_t)j * 32);
        const float4* wg = (const float4*)(wih2 + (size_t)(64 + j) * 32);
        const float4* wo = (const float4*)(wih2 + (size_t)(96 + j) * 32);
        float gi = bih2[j] + bhh2[j];
        float gg = bih2[64 + j] + bhh2[64 + j];
        float go = bih2[96 + j] + bhh2[96 + j];
#pragma unroll
        for (int q = 0; q < 8; ++q) {
            float4 a = wi[q], b = wg[q], c = wo[q];
            float s0 = H1v[4 * q], s1 = H1v[4 * q + 1], s2 = H1v[4 * q + 2], s3 = H1v[4 * q + 3];
            gi += a.x * s0 + a.y * s1 + a.z * s2 + a.w * s3;
            gg += b.x * s0 + b.y * s1 + b.z * s2 + b.w * s3;
            go += c.x * s0 + c.y * s1 + c.z * s2 + c.w * s3;
        }
        float cc = tanhf(gg) / (1.0f + __expf(-gi));
        float hh = tanhf(cc) / (1.0f + __expf(-go));
        oa += fmaxf(hh, 0.0f) * lw[32 + j];
    }

    if (act) {
        const float4 xv = *(const float4*)(x + (size_t)nn * 4);
        oa += fmaxf(xv.x, 0.0f) * lw[64] + fmaxf(xv.y, 0.0f) * lw[65] +
              fmaxf(xv.z, 0.0f) * lw[66] + fmaxf(xv.w, 0.0f) * lw[67];
        out[nn] = oa;
    }
}

// ================= fallback (atomic scatter, fp32) =================

__global__ void k_initdeg(float* __restrict__ deg, int n) {
    int i = blockIdx.x * blockDim.x + threadIdx.x;
    if (i < n) deg[i] = 1.0f;
}

__global__ void k_deg_only(const int* __restrict__ dst, const float* __restrict__ ew,
                           float* __restrict__ deg, int E) {
    int e = blockIdx.x * blockDim.x + threadIdx.x;
    if (e < E) atomicAdd(&deg[dst[e]], ew[e]);
}

__global__ void k_dinv_f(float* __restrict__ deg, int n) {
    int i = blockIdx.x * blockDim.x + threadIdx.x;
    if (i < n) {
        float d = deg[i];
        deg[i] = d > 0.0f ? rsqrtf(d) : 0.0f;
    }
}

__global__ void k_xw1_f(const float* __restrict__ x, const float* __restrict__ W,
                        float* __restrict__ out, int n) {
    int idx = blockIdx.x * blockDim.x + threadIdx.x;
    if (idx >= n * HF) return;
    int nn = idx >> 5, f = idx & 31;
    const float4 xr = *(const float4*)(x + (size_t)nn * 4);
    out[idx] = xr.x * W[f] + xr.y * W[32 + f] + xr.z * W[64 + f] + xr.w * W[96 + f];
}

__global__ void k_xw2_f(const float* __restrict__ Hin, const float* __restrict__ W,
                        float* __restrict__ out, int n) {
    __shared__ float sW[32 * 32];
    __shared__ float sH[8][32];
    int tid = threadIdx.x;
    for (int i = tid; i < 1024; i += 256) sW[i] = W[i];
    int r = tid >> 5, f = tid & 31;
    int nn = blockIdx.x * 8 + r;
    if (nn < n) sH[r][f] = Hin[(size_t)nn * HF + f];
    __syncthreads();
    if (nn >= n) return;
    float acc = 0.0f;
#pragma unroll
    for (int k = 0; k < 32; ++k) acc += sH[r][k] * sW[k * 32 + f];
    out[(size_t)nn * HF + f] = acc;
}

__global__ void k_selfloop(const float* __restrict__ A, const float* __restrict__ dinv,
                           float* __restrict__ B, int n) {
    int idx = blockIdx.x * blockDim.x + threadIdx.x;
    if (idx >= n * HF) return;
    int nn = idx >> 5;
    float di = dinv[nn];
    B[idx] = di * di * A[idx];
}

__global__ void k_scatter(const int* __restrict__ src, const int* __restrict__ dst,
                          const float* __restrict__ ew, const float* __restrict__ dinv,
                          const float* __restrict__ A, float* __restrict__ B, int total) {
    int idx = blockIdx.x * blockDim.x + threadIdx.x;
    if (idx >= total) return;
    int e = idx >> 5, f = idx & 31;
    int s = src[e], d = dst[e];
    float norm = dinv[s] * ew[e] * dinv[d];
    atomicAdd(&B[d * HF + f], norm * A[s * HF + f]);
}

__global__ void k_post(const float* __restrict__ B, const float* __restrict__ bias,
                       const float* __restrict__ gamma, const float* __restrict__ beta,
                       const float* __restrict__ mean, const float* __restrict__ var,
                       float* __restrict__ Hout, int n) {
    int idx = blockIdx.x * blockDim.x + threadIdx.x;
    if (idx >= n * HF) return;
    int f = idx & 31;
    float v = fmaxf(B[idx] + bias[f], 0.0f);
    float sc = gamma[f] * rsqrtf(var[f] + BN_EPS);
    Hout[idx] = (v - mean[f]) * sc + beta[f];
}

// ================= launch =================

extern "C" void kernel_launch(void* const* d_in, const int* in_sizes, int n_in,
                              void* d_out, int out_size, void* d_ws, size_t ws_size,
                              hipStream_t stream) {
    const float* x   = (const float*)d_in[0];
    const int*   ei  = (const int*)d_in[1];
    const float* ew  = (const float*)d_in[2];
    const float* g1w = (const float*)d_in[3];
    const float* g1b = (const float*)d_in[4];
    const float* g2w = (const float*)d_in[5];
    const float* g2b = (const float*)d_in[6];
    const float* bn1g = (const float*)d_in[7];
    const float* bn1b = (const float*)d_in[8];
    const float* bn1m = (const float*)d_in[9];
    const float* bn1v = (const float*)d_in[10];
    const float* bn2g = (const float*)d_in[11];
    const float* bn2b = (const float*)d_in[12];
    const float* bn2m = (const float*)d_in[13];
    const float* bn2v = (const float*)d_in[14];
    const float* w1ih = (const float*)d_in[15];
    const float* b1ih = (const float*)d_in[17];
    const float* b1hh = (const float*)d_in[18];
    const float* w2ih = (const float*)d_in[19];
    const float* b2ih = (const float*)d_in[21];
    const float* b2hh = (const float*)d_in[22];
    const float* lw   = (const float*)d_in[23];
    const float* lb   = (const float*)d_in[24];
    float* out = (float*)d_out;

    const int N = in_sizes[0] / 4;
    const int E = in_sizes[2];
    const int* src = ei;
    const int* dst = ei + E;

    const int T = 256;
    const int NB = (N + BS - 1) / BS;
    long long meanb = ((long long)BS * E) / (N > 0 ? N : 1);
    int bcap = (int)(meanb + meanb / 4 + 128);

    // workspace layout (256B-aligned regions)
    char* p = (char*)d_ws;
    auto alloc = [&](size_t bytes) { char* q = p; p += (bytes + 255) & ~(size_t)255; return q; };
    int*      gcur   = (int*)alloc(sizeof(int) * NB);
    uint2*    recs   = (uint2*)alloc(sizeof(uint2) * (size_t)NB * bcap);
    float*    dinv   = (float*)alloc(sizeof(float) * N);
    int*      pstart = (int*)alloc(sizeof(int) * N);
    int*      pcnt   = (int*)alloc(sizeof(int) * N);
    __half*   A      = (__half*)alloc(sizeof(__half) * (size_t)N * HF);
    float*    C      = (float*)alloc(sizeof(float) * (size_t)N * HF);   // h1
    float*    B2     = (float*)alloc(sizeof(float) * (size_t)N * HF);   // h2
    size_t need = (size_t)(p - (char*)d_ws);

    int bN  = (N + T - 1) / T;
    int bE  = (E + T - 1) / T;
    int bNF = (N * HF + T - 1) / T;
    int bN8 = (N + 7) / 8;
    int bG  = (N + 63) / 64;
    int bH  = (N + 255) / 256;
    int bBin = (E + KEDGE - 1) / KEDGE;

    if (ws_size >= need && NB <= MAXNB && bcap <= BCAPS && N <= (1 << 24)) {
        // ---- build ----
        k_zero<<<(NB + T - 1) / T, T, 0, stream>>>(gcur, NB);
        k_binsort<<<bBin, T, 0, stream>>>(src, dst, ew, E, NB, bcap, gcur, recs);
        k_sortb<<<NB, 512, 0, stream>>>(recs, gcur, bcap, pstart, pcnt, dinv, N);
        k_norm<<<NB * 4, T, 0, stream>>>(recs, gcur, bcap, dinv);

        // ---- layer 1 ----
        k_xw1_h<<<bNF, T, 0, stream>>>(x, g1w, A, N);
        k_gather<<<bG, T, 0, stream>>>(recs, pstart, pcnt, dinv, A,
                                       g1b, bn1g, bn1b, bn1m, bn1v, C, N);
        // ---- layer 2 ----
        k_xw2_h<<<bN8, T, 0, stream>>>(C, g2w, A, N);
        k_gather<<<bG, T, 0, stream>>>(recs, pstart, pcnt, dinv, A,
                                       g2b, bn2g, bn2b, bn2m, bn2v, B2, N);
        // ---- head ----
        k_head<<<bH, T, 0, stream>>>(C, B2, x, w1ih, b1ih, b1hh, w2ih, b2ih, b2hh,
                                     lw, lb, out, N);
    } else {
        // ---- fallback: atomic scatter, fp32 ----
        size_t Npad = ((size_t)N + 255) & ~(size_t)255;
        float* fdinv = (float*)d_ws;
        float* fA = fdinv + Npad;
        float* fB = fA + (size_t)N * HF;
        float* fC = fB + (size_t)N * HF;
        int bEF = (int)(((long long)E * HF + T - 1) / T);

        k_initdeg<<<bN, T, 0, stream>>>(fdinv, N);
        k_deg_only<<<bE, T, 0, stream>>>(dst, ew, fdinv, E);
        k_dinv_f<<<bN, T, 0, stream>>>(fdinv, N);

        k_xw1_f<<<bNF, T, 0, stream>>>(x, g1w, fA, N);
        k_selfloop<<<bNF, T, 0, stream>>>(fA, fdinv, fB, N);
        k_scatter<<<bEF, T, 0, stream>>>(src, dst, ew, fdinv, fA, fB, E * HF);
        k_post<<<bNF, T, 0, stream>>>(fB, g1b, bn1g, bn1b, bn1m, bn1v, fC, N);

        k_xw2_f<<<bN8, T, 0, stream>>>(fC, g2w, fA, N);
        k_selfloop<<<bNF, T, 0, stream>>>(fA, fdinv, fB, N);
        k_scatter<<<bEF, T, 0, stream>>>(src, dst, ew, fdinv, fA, fB, E * HF);
        k_post<<<bNF, T, 0, stream>>>(fB, g2b, bn2g, bn2b, bn2m, bn2v, fB, N);

        k_head<<<bH, T, 0, stream>>>(fC, fB, x, w1ih, b1ih, b1hh, w2ih, b2ih, b2hh,
                                     lw, lb, out, N);
    }
}